// Round 7
// baseline (11127.514 us; speedup 1.0000x reference)
//
#include <hip/hip_runtime.h>

typedef unsigned char u8;
typedef unsigned short u16;
typedef unsigned int u32;
typedef unsigned long long u64;
typedef short short8 __attribute__((ext_vector_type(8)));
typedef __bf16 bf16x8 __attribute__((ext_vector_type(8)));
typedef float f32x4 __attribute__((ext_vector_type(4)));
typedef float f32x2 __attribute__((ext_vector_type(2)));

#define DEV static __device__ __forceinline__

// ---------------------------------------------------------------- params
struct Params {
  const float *x, *eps;
  const float *Wih_ef, *Whh_ef, *bih_ef, *bhh_ef;
  const float *Wih_eb, *Whh_eb, *bih_eb, *bhh_eb;
  const float *W_mu0, *b_mu0, *W_lv0, *b_lv0;
  const float *Wih_c, *Whh_c, *bih_c, *bhh_c;
  const float *W_cmu, *b_cmu, *W_clv, *b_clv;
  const float *Wih_g, *Whh_g, *bih_g, *bhh_g;
  const float *W_f, *b_f, *W_r, *b_r;
  // workspace
  u8  *Xf8;                 // [T][B][256] fp8
  u16 *ebf;                 // [T][B][64] bf16 eps
  u16 *wihcbf;              // [768][256] bf16 (ctrl x-part, k_gx A)
  float *bfc;               // [768] fused bias for Gxc
  u8 *wihef8, *whhef8, *wiheb8, *whheb8;    // enc fp8 [768][256]
  u8 *whhc8, *whhg8;                        // cg fp8 [768][256]
  u8 *wihcf8, *wihg8;                       // fp8 [768][64]
  u8 *wf8;                                  // fp8 [64][256]
  u8 *wcmu8, *wclv8;                        // fp8 [64][256]
  u16 *wrbf;                                // [256][64] bf16 (k_post)
  float *cbn;               // [256]  bhh_c n-gate
  float *gb;                // [4][256] gen biases r,z,in,hn
  float *hdb;               // [128] b_cmu|b_clv
  float *fb2;               // [64]  b_f
  float *eb;                // [2][4][256] enc biases
  float *henc;              // [2*256][256] final enc h (f32)
  float *klacc;             // [16]
  float *klics;             // [32]
  u8 *Gxc;                  // [T][B][768] fp8 -> parked in d_out rates region
  float *out;
};

constexpr size_t RATES_N = 33554432ull;       // 256*512*256
constexpr size_t FOUT    = RATES_N + 2ull;    // factors_all offset in d_out

// ---------------------------------------------------------------- scalar helpers
DEV u16 f2bf(float x) {
  unsigned u = __builtin_bit_cast(unsigned, x);
  u = (u + 0x7FFFu + ((u >> 16) & 1u)) >> 16;   // RNE
  return (u16)u;
}
DEV float bf2f(u32 s) { return __builtin_bit_cast(float, s << 16); }
DEV unsigned f2e4m3(float x) {                   // manual OCP e4m3fn (RNE)
  unsigned u = __builtin_bit_cast(unsigned, x);
  unsigned s = (u >> 24) & 0x80u;
  float ax = __builtin_bit_cast(float, u & 0x7FFFFFFFu);
  if (ax > 448.f) return s | 0x7E;
  if (ax < 0.0009765625f) return s;
  if (ax < 0.015625f) {
    int m = (int)rintf(ax * 512.f);
    if (m >= 8) return s | 0x08;
    return s | (unsigned)m;
  }
  unsigned au = __builtin_bit_cast(unsigned, ax);
  int E = (int)(au >> 23) - 127;
  unsigned m = au & 0x7FFFFFu;
  unsigned r = (m + 0x7FFFFu + ((m >> 20) & 1u)) >> 20;
  if (r >= 8) { r = 0; ++E; if (E > 8) return s | 0x7E; }
  return s | ((unsigned)(E + 7) << 3) | r;
}
DEV float e4m3tof(unsigned b) {
  unsigned s = (b & 0x80u) << 24;
  unsigned e = (b >> 3) & 15u, m = b & 7u;
  float v;
  if (e) v = __builtin_bit_cast(float, ((e + 120u) << 23) | (m << 20));
  else   v = (float)m * 0.001953125f;
  return __builtin_bit_cast(float, __builtin_bit_cast(unsigned, v) | s);
}
template <bool HI>
DEV unsigned pk2fp8(float a, float b, unsigned old) {
#if __has_builtin(__builtin_amdgcn_cvt_pk_fp8_f32)
  return (unsigned)__builtin_amdgcn_cvt_pk_fp8_f32(a, b, (int)old, HI);
#else
  unsigned p = f2e4m3(a) | (f2e4m3(b) << 8);
  return HI ? ((old & 0xFFFFu) | (p << 16)) : ((old & 0xFFFF0000u) | p);
#endif
}
template <bool HI>
DEV f32x2 pkf32(unsigned w) {
#if __has_builtin(__builtin_amdgcn_cvt_pk_f32_fp8)
  return __builtin_amdgcn_cvt_pk_f32_fp8((int)w, HI);
#else
  unsigned h = HI ? (w >> 16) : w;
  f32x2 r; r[0] = e4m3tof(h & 255u); r[1] = e4m3tof((h >> 8) & 255u); return r;
#endif
}
DEV float sigm(float x) { return 1.f / (1.f + __expf(-x)); }
DEV float ftanh(float x) { float t = __expf(2.f * x); return 1.f - 2.f / (t + 1.f); }
DEV float gru_h(float pr, float pz, float pin, float phn, float hp) {
  float r = sigm(pr), z = sigm(pz);
  float n = ftanh(pin + r * phn);
  return (1.f - z) * n + z * hp;
}

// ---------------------------------------------------------------- MFMA helpers
DEV f32x4 MFMA(short8 a, short8 b, f32x4 c) {
  return __builtin_amdgcn_mfma_f32_16x16x32_bf16(
      __builtin_bit_cast(bf16x8, a), __builtin_bit_cast(bf16x8, b), c, 0, 0, 0);
}
DEV f32x4 mfma8(long a, long b, f32x4 c) {       // A=rows(j), B=cols(batch)
  return __builtin_amdgcn_mfma_f32_16x16x32_fp8_fp8(a, b, c, 0, 0, 0);
}
DEV short8 ldfrag(const u16* p0, int stride) {
  const int l = threadIdx.x & 63;
  const u16* p = p0 + (size_t)(l & 15) * stride + ((l >> 4) << 3);
  return *reinterpret_cast<const short8*>(p);
}
DEV short8 ldfrag_f32(const float* p0, int stride) {
  const int l = threadIdx.x & 63;
  const float* p = p0 + (size_t)(l & 15) * stride + ((l >> 4) << 3);
  f32x4 a = *reinterpret_cast<const f32x4*>(p);
  f32x4 b = *reinterpret_cast<const f32x4*>(p + 4);
  short8 r;
  r[0]=(short)f2bf(a[0]); r[1]=(short)f2bf(a[1]); r[2]=(short)f2bf(a[2]); r[3]=(short)f2bf(a[3]);
  r[4]=(short)f2bf(b[0]); r[5]=(short)f2bf(b[1]); r[6]=(short)f2bf(b[2]); r[7]=(short)f2bf(b[3]);
  return r;
}
// global fp8 A-fragment readers; k = kk*32 + (lane>>4)*8 + e (A/B share k-map -> cancels)
DEV long glbW8(const u8* w, int r0, int kk) {        // rowlen 256
  int l = threadIdx.x & 63;
  return *(const long*)(w + (size_t)(r0 + (l & 15)) * 256 + kk * 32 + ((l >> 4) << 3));
}
DEV long glbW8_64(const u8* w, int r0, int k2) {     // rowlen 64
  int l = threadIdx.x & 63;
  return *(const long*)(w + (size_t)(r0 + (l & 15)) * 64 + k2 * 32 + ((l >> 4) << 3));
}
// ---------- fragment-native LDS layout (16-row groups, 8B k-chunks) ----------
DEV int fragoff(int row, int jb) { return jb * 128 + ((row ^ (jb & 15)) << 3); }
DEV long ldsF(const u8* m, int r0, int rs, int kk) {
  int l = threadIdx.x & 63;
  int jb = kk * 4 + (l >> 4);
  return *(const long*)(m + ((r0 >> 4) << (rs + 4)) + fragoff(l & 15, jb));
}
DEV void stF(u8* m, int row, int col, unsigned v) {
  *(unsigned*)(m + fragoff(row, col >> 3) + (col & 7)) = v;
}
// bf16 helpers for k_gx
DEV short8 ldsB16(const u8* m, int r0, int kk) {
  int l = threadIdx.x & 63;
  int row = r0 + (l & 15);
  int off = row * 512 + kk * 64 + ((l >> 4) << 4);
  off ^= (row & 7) << 4;
  return *(const short8*)(m + off);
}
DEV void stage16(u8* dst, const u8* src, int nbytes) {
  for (int i = threadIdx.x * 16; i < nbytes; i += blockDim.x * 16) {
    int row = i >> 9;
    int off = i ^ ((row & 7) << 4);
    *(f32x4*)(dst + off) = *(const f32x4*)(src + i);
  }
}

// ---------------------------------------------------------------- k_init
__global__ __launch_bounds__(256) void k_init(Params P) {
  const size_t g  = (size_t)blockIdx.x * 256 + threadIdx.x;
  const size_t gs = (size_t)gridDim.x * 256;
  for (size_t i = g; i < 4194304ull; i += gs) {
    size_t flat = i << 3;
    int b = (int)(flat >> 17);
    int rem = (int)(flat & 131071);
    int t = rem >> 8, d = rem & 255;
    const float* s = P.x + flat;
    f32x4 v0 = *(const f32x4*)s, v1 = *(const f32x4*)(s + 4);
    u64 p8 = 0;
    #pragma unroll
    for (int e = 0; e < 4; ++e) p8 |= (u64)f2e4m3(v0[e]) << (8 * e);
    #pragma unroll
    for (int e = 0; e < 4; ++e) p8 |= (u64)f2e4m3(v1[e]) << (8 * (e + 4));
    *(u64*)(P.Xf8 + (((size_t)t * 256 + b) << 8) + d) = p8;
  }
  for (size_t i = g; i < 1048576ull; i += gs) {
    size_t flat = i << 3;
    const float* s = P.eps + flat;
    f32x4 v0 = *(const f32x4*)s, v1 = *(const f32x4*)(s + 4);
    short8 o;
    o[0]=(short)f2bf(v0[0]); o[1]=(short)f2bf(v0[1]); o[2]=(short)f2bf(v0[2]); o[3]=(short)f2bf(v0[3]);
    o[4]=(short)f2bf(v1[0]); o[5]=(short)f2bf(v1[1]); o[6]=(short)f2bf(v1[2]); o[7]=(short)f2bf(v1[3]);
    *reinterpret_cast<short8*>(P.ebf + flat) = o;
  }
  const int gi = (int)g, gsi = (int)gs;
  for (int i = gi; i < 196608; i += gsi) {
    P.wihef8[i] = (u8)f2e4m3(P.Wih_ef[i]);  P.whhef8[i] = (u8)f2e4m3(P.Whh_ef[i]);
    P.wiheb8[i] = (u8)f2e4m3(P.Wih_eb[i]);  P.whheb8[i] = (u8)f2e4m3(P.Whh_eb[i]);
    P.whhc8[i]  = (u8)f2e4m3(P.Whh_c[i]);   P.whhg8[i]  = (u8)f2e4m3(P.Whh_g[i]);
    int r = i >> 8, c = i & 255;
    P.wihcbf[i] = f2bf(P.Wih_c[r * 320 + c]);
  }
  for (int i = gi; i < 49152; i += gsi) {
    int r = i >> 6, c = i & 63;
    P.wihcf8[i] = (u8)f2e4m3(P.Wih_c[r * 320 + 256 + c]);
    P.wihg8[i]  = (u8)f2e4m3(P.Wih_g[i]);
  }
  for (int i = gi; i < 16384; i += gsi) {
    P.wf8[i]   = (u8)f2e4m3(P.W_f[i]);
    P.wcmu8[i] = (u8)f2e4m3(P.W_cmu[i]);
    P.wclv8[i] = (u8)f2e4m3(P.W_clv[i]);
    P.wrbf[i]  = f2bf(P.W_r[i]);
  }
  for (int i = gi; i < 768; i += gsi)
    P.bfc[i] = P.bih_c[i] + (i < 512 ? P.bhh_c[i] : 0.f);
  for (int i = gi; i < 256; i += gsi) {
    P.cbn[i] = P.bhh_c[512 + i];
    P.gb[i]        = P.bih_g[i] + P.bhh_g[i];
    P.gb[256 + i]  = P.bih_g[256 + i] + P.bhh_g[256 + i];
    P.gb[512 + i]  = P.bih_g[512 + i];
    P.gb[768 + i]  = P.bhh_g[512 + i];
    P.eb[i]        = P.bih_ef[i] + P.bhh_ef[i];
    P.eb[256 + i]  = P.bih_ef[256 + i] + P.bhh_ef[256 + i];
    P.eb[512 + i]  = P.bih_ef[512 + i];
    P.eb[768 + i]  = P.bhh_ef[512 + i];
    P.eb[1024 + i] = P.bih_eb[i] + P.bhh_eb[i];
    P.eb[1280 + i] = P.bih_eb[256 + i] + P.bhh_eb[256 + i];
    P.eb[1536 + i] = P.bih_eb[512 + i];
    P.eb[1792 + i] = P.bhh_eb[512 + i];
  }
  for (int i = gi; i < 128; i += gsi) P.hdb[i] = (i < 64) ? P.b_cmu[i] : P.b_clv[i - 64];
  for (int i = gi; i < 64; i += gsi)  P.fb2[i] = P.b_f[i];
}

// ---------------------------------------------------------------- k_gx : Gxc[t][b][768] = fp8(x @ Wih_cx.T + bfc)
__global__ __launch_bounds__(512, 2) void k_gx(Params P) {
  extern __shared__ char smem[];
  u8* sA = (u8*)smem;
  u8* sB = sA + 65536;
  const int nc = blockIdx.x % 6;
  const int tb = blockIdx.x / 6;
  const int t = tb >> 1, bh = tb & 1;
  stage16(sA, (const u8*)(P.wihcbf + (size_t)nc * 128 * 256), 65536);
  for (int i = threadIdx.x * 8; i < 32768; i += 512 * 8) {
    int r = i >> 8, c = i & 255;
    const float* s = P.x + ((size_t)(bh * 128 + r) * 512 + t) * 256 + c;
    f32x4 v0 = *(const f32x4*)s, v1 = *(const f32x4*)(s + 4);
    short8 o;
    o[0]=(short)f2bf(v0[0]); o[1]=(short)f2bf(v0[1]); o[2]=(short)f2bf(v0[2]); o[3]=(short)f2bf(v0[3]);
    o[4]=(short)f2bf(v1[0]); o[5]=(short)f2bf(v1[1]); o[6]=(short)f2bf(v1[2]); o[7]=(short)f2bf(v1[3]);
    int off = (r * 512 + c * 2) ^ ((r & 7) << 4);
    *(short8*)(sB + off) = o;
  }
  __syncthreads();
  const int lane = threadIdx.x & 63, wid = threadIdx.x >> 6;
  const int cl = lane & 15, rq = (lane >> 4) << 2;
  const int nglob = nc * 128 + wid * 16;
  short8 Af[8];
  #pragma unroll
  for (int kk = 0; kk < 8; ++kk) Af[kk] = ldsB16(sA, wid * 16, kk);
  float bq[4];
  #pragma unroll
  for (int q = 0; q < 4; ++q) bq[q] = P.bfc[nglob + rq + q];
  #pragma unroll 1
  for (int bt = 0; bt < 8; ++bt) {
    f32x4 acc = {0.f, 0.f, 0.f, 0.f};
    #pragma unroll
    for (int kk = 0; kk < 8; ++kk)
      acc = MFMA(Af[kk], ldsB16(sB, bt * 16, kk), acc);
    float v0 = acc[0] + bq[0], v1 = acc[1] + bq[1], v2 = acc[2] + bq[2], v3 = acc[3] + bq[3];
    unsigned pw = pk2fp8<false>(v0, v1, 0u); pw = pk2fp8<true>(v2, v3, pw);
    *(u32*)(P.Gxc + ((size_t)t * 256 + bh * 128 + bt * 16 + cl) * 768 + nglob + rq) = pw;
  }
}

// ---------------------------------------------------------------- k_main
// cg: resident = half Whh_c + all small-matrix frags; stream other half + Whh_g from L2.
DEV void cg_role(const Params& P, int blk, char* smem) {
  u8* hc8  = (u8*)smem;                 // 2*4096
  u8* hg8  = hc8 + 8192;                // 2*4096
  u8* f8b  = hg8 + 8192;                // 2*1024
  float* sml  = (float*)(f8b + 2048);   // 16*132*4
  float* sred = sml + 16 * 132;

  const int lane = threadIdx.x & 63, wid = threadIdx.x >> 6;  // 8 waves
  const int cl = lane & 15, rq = (lane >> 4) << 2;
  const int b0 = blk << 4, j0 = wid << 5;
  const int sel = wid >> 2, l0 = (wid & 3) << 4;

  for (int i = threadIdx.x * 4; i < 18432; i += 512 * 4) *(int*)(hc8 + i) = 0;

  // ---- resident weights (fit well under 256 VGPR) ----
  long wC0[3][8];                       // Whh_c, cg2=0 half (48 regs)
  #pragma unroll
  for (int g3 = 0; g3 < 3; ++g3)
    #pragma unroll
    for (int kk = 0; kk < 8; ++kk)
      wC0[g3][kk] = glbW8(P.whhc8, g3 * 256 + j0, kk);
  long wcf[2][3][2], wgu[2][3][2];      // f-part / u-part (24+24 regs)
  #pragma unroll
  for (int cg2 = 0; cg2 < 2; ++cg2)
    #pragma unroll
    for (int g3 = 0; g3 < 3; ++g3)
      #pragma unroll
      for (int k2 = 0; k2 < 2; ++k2) {
        wcf[cg2][g3][k2] = glbW8_64(P.wihcf8, g3 * 256 + j0 + cg2 * 16, k2);
        wgu[cg2][g3][k2] = glbW8_64(P.wihg8,  g3 * 256 + j0 + cg2 * 16, k2);
      }
  long whd[8];                          // head weights for this wave (16 regs)
  { const u8* hw = sel ? P.wclv8 : P.wcmu8;
    #pragma unroll
    for (int kk = 0; kk < 8; ++kk) whd[kk] = glbW8(hw, l0, kk); }
  long wfv[8];                          // W_f frags (wid<4 only)
  if (wid < 4) {
    #pragma unroll
    for (int kk = 0; kk < 8; ++kk) wfv[kk] = glbW8(P.wf8, wid * 16, kk);
  }

  f32x4 hcM[2] = {{0,0,0,0},{0,0,0,0}};
  f32x4 hgM[2] = {{0,0,0,0},{0,0,0,0}};
  float klv = 0.f;
  __syncthreads();

  #pragma unroll 1
  for (int t = 0; t < 512; ++t) {
    const int cur = t & 1, prv = cur ^ 1;
    u8 *hcP = hc8 + prv * 4096, *hcC = hc8 + cur * 4096;
    u8 *hgP = hg8 + prv * 4096, *hgC = hg8 + cur * 4096;
    // ---- early issues: Gxc, eps, streamed Whh_c half (cg2=1) ----
    u32 gx[6];
    { const u8* gp = P.Gxc + ((size_t)t * 256 + b0 + cl) * 768;
      #pragma unroll
      for (int c2 = 0; c2 < 2; ++c2)
        #pragma unroll
        for (int g3 = 0; g3 < 3; ++g3)
          gx[c2 * 3 + g3] = *(const u32*)(gp + g3 * 256 + j0 + c2 * 16 + rq);
    }
    const u16* ep16 = P.ebf + ((size_t)t * 256 + b0 + cl) * 64 + ((lane >> 4) << 3);
    short8 ee0 = *(const short8*)(ep16);
    short8 ee1 = *(const short8*)(ep16 + 32);
    long wC1[3][8];
    #pragma unroll
    for (int g3 = 0; g3 < 3; ++g3)
      #pragma unroll
      for (int kk = 0; kk < 8; ++kk)
        wC1[g3][kk] = glbW8(P.whhc8, g3 * 256 + j0 + 16, kk);
    // ---- P1: controller GRU ----
    long hf[8];
    #pragma unroll
    for (int kk = 0; kk < 8; ++kk) hf[kk] = ldsF(hcP, 0, 8, kk);
    long ff0 = ldsF(f8b + prv * 1024, 0, 6, 0);
    long ff1 = ldsF(f8b + prv * 1024, 0, 6, 1);
    #pragma unroll
    for (int cg2 = 0; cg2 < 2; ++cg2) {
      const int jrow = j0 + cg2 * 16;
      f32x4 ar = {0,0,0,0}, az = {0,0,0,0}, ai = {0,0,0,0}, ah = {0,0,0,0};
      #pragma unroll
      for (int kk = 0; kk < 8; ++kk) {
        long w0 = cg2 ? wC1[0][kk] : wC0[0][kk];
        long w1 = cg2 ? wC1[1][kk] : wC0[1][kk];
        long w2 = cg2 ? wC1[2][kk] : wC0[2][kk];
        ar = mfma8(w0, hf[kk], ar);
        az = mfma8(w1, hf[kk], az);
        ah = mfma8(w2, hf[kk], ah);
      }
      ar = mfma8(wcf[cg2][0][0], ff0, ar);  ar = mfma8(wcf[cg2][0][1], ff1, ar);
      az = mfma8(wcf[cg2][1][0], ff0, az);  az = mfma8(wcf[cg2][1][1], ff1, az);
      ai = mfma8(wcf[cg2][2][0], ff0, ai);  ai = mfma8(wcf[cg2][2][1], ff1, ai);
      f32x4 bn = *(const f32x4*)(P.cbn + jrow + rq);
      f32x2 rlo = pkf32<false>(gx[cg2*3+0]), rhi = pkf32<true>(gx[cg2*3+0]);
      f32x2 zlo = pkf32<false>(gx[cg2*3+1]), zhi = pkf32<true>(gx[cg2*3+1]);
      f32x2 nlo = pkf32<false>(gx[cg2*3+2]), nhi = pkf32<true>(gx[cg2*3+2]);
      float h0 = gru_h(ar[0]+rlo[0], az[0]+zlo[0], ai[0]+nlo[0], ah[0]+bn[0], hcM[cg2][0]);
      float h1 = gru_h(ar[1]+rlo[1], az[1]+zlo[1], ai[1]+nlo[1], ah[1]+bn[1], hcM[cg2][1]);
      float h2 = gru_h(ar[2]+rhi[0], az[2]+zhi[0], ai[2]+nhi[0], ah[2]+bn[2], hcM[cg2][2]);
      float h3 = gru_h(ar[3]+rhi[1], az[3]+zhi[1], ai[3]+nhi[1], ah[3]+bn[3], hcM[cg2][3]);
      hcM[cg2][0] = h0; hcM[cg2][1] = h1; hcM[cg2][2] = h2; hcM[cg2][3] = h3;
      unsigned pw = pk2fp8<false>(h0, h1, 0u); pw = pk2fp8<true>(h2, h3, pw);
      stF(hcC, cl, jrow + rq, pw);
    }
    __syncthreads();                                    // B1
    // ---- P2: heads -> sml ----
    { long hcv[8];
      #pragma unroll
      for (int kk = 0; kk < 8; ++kk) hcv[kk] = ldsF(hcC, 0, 8, kk);
      f32x4 am = {0,0,0,0};
      #pragma unroll
      for (int kk = 0; kk < 8; ++kk) am = mfma8(whd[kk], hcv[kk], am);
      f32x4 hb = *(const f32x4*)(P.hdb + sel * 64 + l0 + rq);
      am += hb;
      *(f32x4*)(sml + cl * 132 + sel * 64 + l0 + rq) = am;
    }
    __syncthreads();                                    // B2
    // ---- P3: u + generator GRU ----
    long wGa[3][8];                                     // stream Whh_g cg2=0
    #pragma unroll
    for (int g3 = 0; g3 < 3; ++g3)
      #pragma unroll
      for (int kk = 0; kk < 8; ++kk)
        wGa[g3][kk] = glbW8(P.whhg8, g3 * 256 + j0, kk);
    long U[2];
    { const float* ml = sml + cl * 132;
      const int kh = (lane >> 4) << 3;
      #pragma unroll
      for (int k2 = 0; k2 < 2; ++k2) {
        f32x4 mu0 = *(const f32x4*)(ml + k2 * 32 + kh);
        f32x4 mu1 = *(const f32x4*)(ml + k2 * 32 + kh + 4);
        f32x4 lv0 = *(const f32x4*)(ml + 64 + k2 * 32 + kh);
        f32x4 lv1 = *(const f32x4*)(ml + 64 + k2 * 32 + kh + 4);
        short8 ev = k2 ? ee1 : ee0;
        float uu[8];
        #pragma unroll
        for (int e = 0; e < 4; ++e) {
          float epv = bf2f((u32)(u16)ev[e]);
          uu[e] = mu0[e] + epv * __expf(0.5f * lv0[e]);
        }
        #pragma unroll
        for (int e = 0; e < 4; ++e) {
          float epv = bf2f((u32)(u16)ev[4 + e]);
          uu[4 + e] = mu1[e] + epv * __expf(0.5f * lv1[e]);
        }
        unsigned pa = pk2fp8<false>(uu[0], uu[1], 0u); pa = pk2fp8<true>(uu[2], uu[3], pa);
        unsigned pb = pk2fp8<false>(uu[4], uu[5], 0u); pb = pk2fp8<true>(uu[6], uu[7], pb);
        U[k2] = (long)(((u64)pb << 32) | (u64)pa);
      }
    }
    long hg[8];
    #pragma unroll
    for (int kk = 0; kk < 8; ++kk) hg[kk] = ldsF(hgP, 0, 8, kk);
    // cg2 = 0 MFMAs (wGa)
    f32x4 gr = {0,0,0,0}, gz = {0,0,0,0}, gi = {0,0,0,0}, gh = {0,0,0,0};
    #pragma unroll
    for (int kk = 0; kk < 8; ++kk) {
      gr = mfma8(wGa[0][kk], hg[kk], gr);
      gz = mfma8(wGa[1][kk], hg[kk], gz);
      gh = mfma8(wGa[2][kk], hg[kk], gh);
    }
    #pragma unroll
    for (int k2 = 0; k2 < 2; ++k2) {
      gr = mfma8(wgu[0][0][k2], U[k2], gr);
      gz = mfma8(wgu[0][1][k2], U[k2], gz);
      gi = mfma8(wgu[0][2][k2], U[k2], gi);
    }
    long wGb[3][8];                                     // stream Whh_g cg2=1
    #pragma unroll
    for (int g3 = 0; g3 < 3; ++g3)
      #pragma unroll
      for (int kk = 0; kk < 8; ++kk)
        wGb[g3][kk] = glbW8(P.whhg8, g3 * 256 + j0 + 16, kk);
    {
      f32x4 br  = *(const f32x4*)(P.gb +       j0 + rq);
      f32x4 bz  = *(const f32x4*)(P.gb + 256 + j0 + rq);
      f32x4 bi  = *(const f32x4*)(P.gb + 512 + j0 + rq);
      f32x4 bh2 = *(const f32x4*)(P.gb + 768 + j0 + rq);
      float h0 = gru_h(gr[0]+br[0], gz[0]+bz[0], gi[0]+bi[0], gh[0]+bh2[0], hgM[0][0]);
      float h1 = gru_h(gr[1]+br[1], gz[1]+bz[1], gi[1]+bi[1], gh[1]+bh2[1], hgM[0][1]);
      float h2 = gru_h(gr[2]+br[2], gz[2]+bz[2], gi[2]+bi[2], gh[2]+bh2[2], hgM[0][2]);
      float h3 = gru_h(gr[3]+br[3], gz[3]+bz[3], gi[3]+bi[3], gh[3]+bh2[3], hgM[0][3]);
      hgM[0][0] = h0; hgM[0][1] = h1; hgM[0][2] = h2; hgM[0][3] = h3;
      unsigned pw = pk2fp8<false>(h0, h1, 0u); pw = pk2fp8<true>(h2, h3, pw);
      stF(hgC, cl, j0 + rq, pw);
    }
    // cg2 = 1 MFMAs (wGb)
    {
      f32x4 r2 = {0,0,0,0}, z2 = {0,0,0,0}, i2 = {0,0,0,0}, h2a = {0,0,0,0};
      #pragma unroll
      for (int kk = 0; kk < 8; ++kk) {
        r2 = mfma8(wGb[0][kk], hg[kk], r2);
        z2 = mfma8(wGb[1][kk], hg[kk], z2);
        h2a = mfma8(wGb[2][kk], hg[kk], h2a);
      }
      #pragma unroll
      for (int k2 = 0; k2 < 2; ++k2) {
        r2 = mfma8(wgu[1][0][k2], U[k2], r2);
        z2 = mfma8(wgu[1][1][k2], U[k2], z2);
        i2 = mfma8(wgu[1][2][k2], U[k2], i2);
      }
      const int jrow = j0 + 16;
      f32x4 br  = *(const f32x4*)(P.gb +       jrow + rq);
      f32x4 bz  = *(const f32x4*)(P.gb + 256 + jrow + rq);
      f32x4 bi  = *(const f32x4*)(P.gb + 512 + jrow + rq);
      f32x4 bh2 = *(const f32x4*)(P.gb + 768 + jrow + rq);
      float h0 = gru_h(r2[0]+br[0], z2[0]+bz[0], i2[0]+bi[0], h2a[0]+bh2[0], hgM[1][0]);
      float h1 = gru_h(r2[1]+br[1], z2[1]+bz[1], i2[1]+bi[1], h2a[1]+bh2[1], hgM[1][1]);
      float h2 = gru_h(r2[2]+br[2], z2[2]+bz[2], i2[2]+bi[2], h2a[2]+bh2[2], hgM[1][2]);
      float h3 = gru_h(r2[3]+br[3], z2[3]+bz[3], i2[3]+bi[3], h2a[3]+bh2[3], hgM[1][3]);
      hgM[1][0] = h0; hgM[1][1] = h1; hgM[1][2] = h2; hgM[1][3] = h3;
      unsigned pw = pk2fp8<false>(h0, h1, 0u); pw = pk2fp8<true>(h2, h3, pw);
      stF(hgC, cl, jrow + rq, pw);
    }
    __syncthreads();                                    // B3
    // ---- P4: factors + KL ----
    if (wid < 4) {
      long hgv[8];
      #pragma unroll
      for (int kk = 0; kk < 8; ++kk) hgv[kk] = ldsF(hgC, 0, 8, kk);
      f32x4 af = {0,0,0,0};
      #pragma unroll
      for (int kk = 0; kk < 8; ++kk) af = mfma8(wfv[kk], hgv[kk], af);
      f32x4 fb = *(const f32x4*)(P.fb2 + wid * 16 + rq);
      af += fb;
      float* fo = P.out + FOUT + (size_t)(b0 + cl) * 32768 + (size_t)t * 64 + wid * 16 + rq;
      f32x2 lo = {af[0], af[1]}, hi2 = {af[2], af[3]};
      *(f32x2*)fo = lo;
      *(f32x2*)(fo + 2) = hi2;
      unsigned pw = pk2fp8<false>(af[0], af[1], 0u); pw = pk2fp8<true>(af[2], af[3], pw);
      stF(f8b + cur * 1024, cl, wid * 16 + rq, pw);
    } else {
      #pragma unroll
      for (int e = 0; e < 4; ++e) {
        int p = ((wid - 4) * 64 + lane) * 4 + e;
        int row = p >> 6, l = p & 63;
        float mu = sml[row * 132 + l], lv = sml[row * 132 + 64 + l];
        klv += __expf(lv) + mu * mu - 1.f - lv;
      }
    }
    __syncthreads();                                    // B4
  }
  if (wid >= 4) {
    float v = klv;
    v += __shfl_down(v, 32); v += __shfl_down(v, 16); v += __shfl_down(v, 8);
    v += __shfl_down(v, 4);  v += __shfl_down(v, 2);  v += __shfl_down(v, 1);
    if (lane == 0) sred[wid] = v;
  }
  __syncthreads();
  if (threadIdx.x == 0) P.klacc[blk] = sred[4] + sred[5] + sred[6] + sred[7];
}

DEV void enc_role(const Params& P, int dir, int b0, char* smem) {
  u8* h8 = (u8*)smem;                   // 2*4096 state
  u8* sx = h8 + 8192;                   // 2*4096 x tile dbuf
  const int lane = threadIdx.x & 63, wid = threadIdx.x >> 6;
  const int cl = lane & 15, rq = (lane >> 4) << 2;
  const int j0 = wid << 5;
  const u8* wih8 = dir ? P.wiheb8 : P.wihef8;
  const u8* whh8 = dir ? P.whheb8 : P.whhef8;
  const float* ebt = P.eb + dir * 1024;
  for (int i = threadIdx.x * 4; i < 8192; i += 512 * 4) *(int*)(h8 + i) = 0;
  long wH0[3][8];                       // resident Whh half (cg2=0)
  #pragma unroll
  for (int g3 = 0; g3 < 3; ++g3)
    #pragma unroll
    for (int kk = 0; kk < 8; ++kk)
      wH0[g3][kk] = glbW8(whh8, g3 * 256 + j0, kk);
  f32x4 heM[2] = {{0,0,0,0},{0,0,0,0}};
  const int ssrc = threadIdx.x * 8;
  const int sdst = fragoff(threadIdx.x >> 5, threadIdx.x & 31);
  const int t0 = dir ? 511 : 0;
  *(u64*)(sx + sdst) = *(const u64*)(P.Xf8 + (((size_t)t0 * 256 + b0) << 8) + ssrc);
  __syncthreads();

  #pragma unroll 1
  for (int i = 0; i < 512; ++i) {
    const int cur = i & 1, prv = cur ^ 1;
    const int t = dir ? (511 - i) : i;
    u8 *hP = h8 + prv * 4096, *hC = h8 + cur * 4096;
    const u8* sxc = sx + cur * 4096;
    // early issues: next-x prefetch, streamed Whh half1 + Wih half0
    u64 xpre = 0;
    if (i < 511) {
      int tn = dir ? (t - 1) : (t + 1);
      xpre = *(const u64*)(P.Xf8 + (((size_t)tn * 256 + b0) << 8) + ssrc);
    }
    long wH1[3][8], wIa[3][8];
    #pragma unroll
    for (int g3 = 0; g3 < 3; ++g3)
      #pragma unroll
      for (int kk = 0; kk < 8; ++kk) {
        wH1[g3][kk] = glbW8(whh8, g3 * 256 + j0 + 16, kk);
        wIa[g3][kk] = glbW8(wih8, g3 * 256 + j0, kk);
      }
    long hp[8], xv[8];
    #pragma unroll
    for (int kk = 0; kk < 8; ++kk) { hp[kk] = ldsF(hP, 0, 8, kk); xv[kk] = ldsF(sxc, 0, 8, kk); }
    // cg2 = 0
    f32x4 er = {0,0,0,0}, ez = {0,0,0,0}, ei = {0,0,0,0}, eh = {0,0,0,0};
    #pragma unroll
    for (int kk = 0; kk < 8; ++kk) {
      er = mfma8(wH0[0][kk], hp[kk], er);
      ez = mfma8(wH0[1][kk], hp[kk], ez);
      eh = mfma8(wH0[2][kk], hp[kk], eh);
    }
    #pragma unroll
    for (int kk = 0; kk < 8; ++kk) {
      er = mfma8(wIa[0][kk], xv[kk], er);
      ez = mfma8(wIa[1][kk], xv[kk], ez);
      ei = mfma8(wIa[2][kk], xv[kk], ei);
    }
    long wIb[3][8];                                    // stream Wih half1
    #pragma unroll
    for (int g3 = 0; g3 < 3; ++g3)
      #pragma unroll
      for (int kk = 0; kk < 8; ++kk)
        wIb[g3][kk] = glbW8(wih8, g3 * 256 + j0 + 16, kk);
    {
      f32x4 br  = *(const f32x4*)(ebt +       j0 + rq);
      f32x4 bz  = *(const f32x4*)(ebt + 256 + j0 + rq);
      f32x4 bi  = *(const f32x4*)(ebt + 512 + j0 + rq);
      f32x4 bh2 = *(const f32x4*)(ebt + 768 + j0 + rq);
      float h0 = gru_h(er[0]+br[0], ez[0]+bz[0], ei[0]+bi[0], eh[0]+bh2[0], heM[0][0]);
      float h1 = gru_h(er[1]+br[1], ez[1]+bz[1], ei[1]+bi[1], eh[1]+bh2[1], heM[0][1]);
      float h2 = gru_h(er[2]+br[2], ez[2]+bz[2], ei[2]+bi[2], eh[2]+bh2[2], heM[0][2]);
      float h3 = gru_h(er[3]+br[3], ez[3]+bz[3], ei[3]+bi[3], eh[3]+bh2[3], heM[0][3]);
      heM[0][0] = h0; heM[0][1] = h1; heM[0][2] = h2; heM[0][3] = h3;
      unsigned pw = pk2fp8<false>(h0, h1, 0u); pw = pk2fp8<true>(h2, h3, pw);
      stF(hC, cl, j0 + rq, pw);
    }
    // cg2 = 1
    {
      f32x4 r2 = {0,0,0,0}, z2 = {0,0,0,0}, i2 = {0,0,0,0}, h2a = {0,0,0,0};
      #pragma unroll
      for (int kk = 0; kk < 8; ++kk) {
        r2 = mfma8(wH1[0][kk], hp[kk], r2);
        z2 = mfma8(wH1[1][kk], hp[kk], z2);
        h2a = mfma8(wH1[2][kk], hp[kk], h2a);
      }
      #pragma unroll
      for (int kk = 0; kk < 8; ++kk) {
        r2 = mfma8(wIb[0][kk], xv[kk], r2);
        z2 = mfma8(wIb[1][kk], xv[kk], z2);
        i2 = mfma8(wIb[2][kk], xv[kk], i2);
      }
      const int jrow = j0 + 16;
      f32x4 br  = *(const f32x4*)(ebt +       jrow + rq);
      f32x4 bz  = *(const f32x4*)(ebt + 256 + jrow + rq);
      f32x4 bi  = *(const f32x4*)(ebt + 512 + jrow + rq);
      f32x4 bh2 = *(const f32x4*)(ebt + 768 + jrow + rq);
      float h0 = gru_h(r2[0]+br[0], z2[0]+bz[0], i2[0]+bi[0], h2a[0]+bh2[0], heM[1][0]);
      float h1 = gru_h(r2[1]+br[1], z2[1]+bz[1], i2[1]+bi[1], h2a[1]+bh2[1], heM[1][1]);
      float h2 = gru_h(r2[2]+br[2], z2[2]+bz[2], i2[2]+bi[2], h2a[2]+bh2[2], heM[1][2]);
      float h3 = gru_h(r2[3]+br[3], z2[3]+bz[3], i2[3]+bi[3], h2a[3]+bh2[3], heM[1][3]);
      heM[1][0] = h0; heM[1][1] = h1; heM[1][2] = h2; heM[1][3] = h3;
      unsigned pw = pk2fp8<false>(h0, h1, 0u); pw = pk2fp8<true>(h2, h3, pw);
      stF(hC, cl, jrow + rq, pw);
    }
    if (i < 511) *(u64*)(sx + prv * 4096 + sdst) = xpre;
    __syncthreads();
  }
  #pragma unroll
  for (int cg2 = 0; cg2 < 2; ++cg2)
    *(f32x4*)(P.henc + (size_t)(dir * 256 + b0 + cl) * 256 + j0 + cg2 * 16 + rq) = heM[cg2];
}

__global__ __launch_bounds__(512) void k_main(Params P) {
  extern __shared__ char smem[];
  const int blk = blockIdx.x;
  if (blk < 16) cg_role(P, blk, smem);
  else {
    const int e = blk - 16;
    enc_role(P, e >> 4, (e & 15) << 4, smem);
  }
}

// ---------------------------------------------------------------- k_post: IC heads + rates
__global__ __launch_bounds__(256) void k_post(Params P) {
  const int blk = blockIdx.x;
  if (blk < 32) {
    __shared__ float red[4];
    float ka = 0.f;
    #pragma unroll 1
    for (int pp = 0; pp < 2; ++pp) {
      int p = blk * 512 + threadIdx.x * 2 + pp;
      int b = p >> 6, l = p & 63;
      float mu = P.b_mu0[l], lv = P.b_lv0[l];
      const float* wm = P.W_mu0 + (size_t)l * 512;
      const float* wl = P.W_lv0 + (size_t)l * 512;
      const float* h0 = P.henc + (size_t)b * 256;
      const float* h1 = P.henc + (size_t)(256 + b) * 256;
      #pragma unroll 4
      for (int k = 0; k < 256; ++k) {
        float hf = h0[k], hb = h1[k];
        mu += hf * wm[k] + hb * wm[256 + k];
        lv += hf * wl[k] + hb * wl[256 + k];
      }
      ka += __expf(lv) + mu * mu - 1.f - lv;
    }
    const int lane = threadIdx.x & 63, wid = threadIdx.x >> 6;
    ka += __shfl_down(ka, 32); ka += __shfl_down(ka, 16); ka += __shfl_down(ka, 8);
    ka += __shfl_down(ka, 4);  ka += __shfl_down(ka, 2);  ka += __shfl_down(ka, 1);
    if (lane == 0) red[wid] = ka;
    __syncthreads();
    if (threadIdx.x == 0) P.klics[blk] = red[0] + red[1] + red[2] + red[3];
  } else {
    const int lane = threadIdx.x & 63, wid = threadIdx.x >> 6;
    const int cl = lane & 15, rq = (lane >> 4) << 2;
    const int gw = (blk - 32) * 4 + wid;
    const size_t r0 = (size_t)gw << 4;
    const float* Fs = P.out + FOUT;
    short8 F0 = ldfrag_f32(Fs + r0 * 64, 64);
    short8 F1 = ldfrag_f32(Fs + r0 * 64 + 32, 64);
    #pragma unroll 1
    for (int ct = 0; ct < 16; ++ct) {
      const int d0 = ct << 4;
      const u16* W = P.wrbf + (size_t)d0 * 64;
      f32x4 a = {0,0,0,0};
      a = MFMA(ldfrag(W, 64), F0, a);
      a = MFMA(ldfrag(W + 32, 64), F1, a);
      f32x4 rb = *(const f32x4*)(P.b_r + d0 + rq);
      f32x4 o;
      o[0] = __expf(a[0] + rb[0]); o[1] = __expf(a[1] + rb[1]);
      o[2] = __expf(a[2] + rb[2]); o[3] = __expf(a[3] + rb[3]);
      *(f32x4*)(P.out + (r0 + cl) * 256 + d0 + rq) = o;
    }
  }
}

__global__ void k_final(Params P) {
  if (threadIdx.x == 0) {
    float s = 0.f, s2 = 0.f;
    for (int i = 0; i < 16; ++i) s += P.klacc[i];
    for (int i = 0; i < 32; ++i) s2 += P.klics[i];
    P.out[RATES_N]     = s2 * (0.5f / 256.f);
    P.out[RATES_N + 1] = s  * (0.5f / (256.f * 512.f));
  }
}

// ---------------------------------------------------------------- launch
extern "C" void kernel_launch(void* const* d_in, const int* in_sizes, int n_in,
                              void* d_out, int out_size, void* d_ws, size_t ws_size,
                              hipStream_t stream) {
  (void)in_sizes; (void)n_in; (void)out_size; (void)ws_size;
  Params P;
  const float* const* in = (const float* const*)d_in;
  P.x = in[0];      P.eps = in[1];
  P.Wih_ef = in[2]; P.Whh_ef = in[3]; P.bih_ef = in[4]; P.bhh_ef = in[5];
  P.Wih_eb = in[6]; P.Whh_eb = in[7]; P.bih_eb = in[8]; P.bhh_eb = in[9];
  P.W_mu0 = in[10]; P.b_mu0 = in[11]; P.W_lv0 = in[12]; P.b_lv0 = in[13];
  P.Wih_c = in[14]; P.Whh_c = in[15]; P.bih_c = in[16]; P.bhh_c = in[17];
  P.W_cmu = in[18]; P.b_cmu = in[19]; P.W_clv = in[20]; P.b_clv = in[21];
  P.Wih_g = in[22]; P.Whh_g = in[23]; P.bih_g = in[24]; P.bhh_g = in[25];
  P.W_f = in[26];   P.b_f = in[27];   P.W_r = in[28];   P.b_r = in[29];

  char* w = (char*)d_ws;
  size_t off = 0;
  auto take = [&](size_t bytes) -> char* {
    char* r = w + off;
    off = (off + bytes + 255) & ~(size_t)255;
    return r;
  };
  P.Xf8    = (u8*)take(33554432ull);
  P.ebf    = (u16*)take(16777216ull * 2);
  P.wihcbf = (u16*)take(196608ull * 2);
  P.bfc    = (float*)take(768ull * 4);
  P.wihef8 = (u8*)take(196608ull);
  P.whhef8 = (u8*)take(196608ull);
  P.wiheb8 = (u8*)take(196608ull);
  P.whheb8 = (u8*)take(196608ull);
  P.whhc8  = (u8*)take(196608ull);
  P.whhg8  = (u8*)take(196608ull);
  P.wihcf8 = (u8*)take(49152ull);
  P.wihg8  = (u8*)take(49152ull);
  P.wf8    = (u8*)take(16384ull);
  P.wcmu8  = (u8*)take(16384ull);
  P.wclv8  = (u8*)take(16384ull);
  P.wrbf   = (u16*)take(16384ull * 2);
  P.cbn    = (float*)take(256ull * 4);
  P.gb     = (float*)take(1024ull * 4);
  P.hdb    = (float*)take(128ull * 4);
  P.fb2    = (float*)take(64ull * 4);
  P.eb     = (float*)take(2048ull * 4);
  P.henc   = (float*)take(131072ull * 4);
  P.klacc  = (float*)take(64ull * 4);
  P.klics  = (float*)take(64ull * 4);
  P.Gxc    = (u8*)d_out;                 // [T][B][768] parked in rates region
  P.out    = (float*)d_out;

  hipLaunchKernelGGL(k_init,  dim3(2048), dim3(256), 0, stream, P);
  hipLaunchKernelGGL(k_gx,    dim3(6144), dim3(512), 131072, stream, P);
  hipLaunchKernelGGL(k_main,  dim3(48),   dim3(512), 27008, stream, P);
  hipLaunchKernelGGL(k_post,  dim3(2080), dim3(256), 0, stream, P);
  hipLaunchKernelGGL(k_final, dim3(1),    dim3(64),  0, stream, P);
}

// Round 8
// 4711.859 us; speedup vs baseline: 2.3616x; 2.3616x over previous
//
#include <hip/hip_runtime.h>

typedef unsigned char u8;
typedef unsigned short u16;
typedef unsigned int u32;
typedef unsigned long long u64;
typedef short short8 __attribute__((ext_vector_type(8)));
typedef __bf16 bf16x8 __attribute__((ext_vector_type(8)));
typedef float f32x4 __attribute__((ext_vector_type(4)));
typedef float f32x2 __attribute__((ext_vector_type(2)));
typedef long longx2 __attribute__((ext_vector_type(2)));

#define DEV static __device__ __forceinline__

// ---------------------------------------------------------------- params
struct Params {
  const float *x, *eps;
  const float *Wih_ef, *Whh_ef, *bih_ef, *bhh_ef;
  const float *Wih_eb, *Whh_eb, *bih_eb, *bhh_eb;
  const float *W_mu0, *b_mu0, *W_lv0, *b_lv0;
  const float *Wih_c, *Whh_c, *bih_c, *bhh_c;
  const float *W_cmu, *b_cmu, *W_clv, *b_clv;
  const float *Wih_g, *Whh_g, *bih_g, *bhh_g;
  const float *W_f, *b_f, *W_r, *b_r;
  // workspace (all big weights stored FRAGMENT-LINEAR swizzled)
  u8  *Xf8;                 // [T][B][256] fp8 (linear)
  u16 *ebf;                 // eps swizzled: [t][btile][k2][64 lanes][8 bf16]
  u16 *wihcbf;              // [768][256] bf16 (k_gx A)
  float *bfc;               // [768]
  u8 *wihef8, *whhef8, *wiheb8, *whheb8;    // enc, swizzled K=256
  u8 *whhc8, *whhg8;                        // cg, swizzled K=256
  u8 *wihcf8, *wihg8;                       // swizzled K=64
  u8 *wf8, *wcmu8, *wclv8;                  // swizzled K=256 (R=64)
  u16 *wrbf;                                // [256][64] bf16 (k_post)
  float *cbn;               // [256]
  float *gb;                // [4][256]
  float *hdb;               // [128]
  float *fb2;               // [64]
  float *eb;                // [2][4][256]
  float *henc;              // [2*256][256]
  float *klacc;             // [16]
  float *klics;             // [32]
  u8 *Gxc;                  // swizzled: [t][btile][jtile16(48)][64 lanes][4B]
  float *out;
};

constexpr size_t RATES_N = 33554432ull;
constexpr size_t FOUT    = RATES_N + 2ull;

// ---------------------------------------------------------------- scalar helpers
DEV u16 f2bf(float x) {
  unsigned u = __builtin_bit_cast(unsigned, x);
  u = (u + 0x7FFFu + ((u >> 16) & 1u)) >> 16;
  return (u16)u;
}
DEV float bf2f(u32 s) { return __builtin_bit_cast(float, s << 16); }
DEV unsigned f2e4m3(float x) {
  unsigned u = __builtin_bit_cast(unsigned, x);
  unsigned s = (u >> 24) & 0x80u;
  float ax = __builtin_bit_cast(float, u & 0x7FFFFFFFu);
  if (ax > 448.f) return s | 0x7E;
  if (ax < 0.0009765625f) return s;
  if (ax < 0.015625f) {
    int m = (int)rintf(ax * 512.f);
    if (m >= 8) return s | 0x08;
    return s | (unsigned)m;
  }
  unsigned au = __builtin_bit_cast(unsigned, ax);
  int E = (int)(au >> 23) - 127;
  unsigned m = au & 0x7FFFFFu;
  unsigned r = (m + 0x7FFFFu + ((m >> 20) & 1u)) >> 20;
  if (r >= 8) { r = 0; ++E; if (E > 8) return s | 0x7E; }
  return s | ((unsigned)(E + 7) << 3) | r;
}
DEV float e4m3tof(unsigned b) {
  unsigned s = (b & 0x80u) << 24;
  unsigned e = (b >> 3) & 15u, m = b & 7u;
  float v;
  if (e) v = __builtin_bit_cast(float, ((e + 120u) << 23) | (m << 20));
  else   v = (float)m * 0.001953125f;
  return __builtin_bit_cast(float, __builtin_bit_cast(unsigned, v) | s);
}
template <bool HI>
DEV unsigned pk2fp8(float a, float b, unsigned old) {
#if __has_builtin(__builtin_amdgcn_cvt_pk_fp8_f32)
  return (unsigned)__builtin_amdgcn_cvt_pk_fp8_f32(a, b, (int)old, HI);
#else
  unsigned p = f2e4m3(a) | (f2e4m3(b) << 8);
  return HI ? ((old & 0xFFFFu) | (p << 16)) : ((old & 0xFFFF0000u) | p);
#endif
}
template <bool HI>
DEV f32x2 pkf32(unsigned w) {
#if __has_builtin(__builtin_amdgcn_cvt_pk_f32_fp8)
  return __builtin_amdgcn_cvt_pk_f32_fp8((int)w, HI);
#else
  unsigned h = HI ? (w >> 16) : w;
  f32x2 r; r[0] = e4m3tof(h & 255u); r[1] = e4m3tof((h >> 8) & 255u); return r;
#endif
}
DEV float sigm(float x) { return 1.f / (1.f + __expf(-x)); }
DEV float ftanh(float x) { float t = __expf(2.f * x); return 1.f - 2.f / (t + 1.f); }
DEV float gru_h(float pr, float pz, float pin, float phn, float hp) {
  float r = sigm(pr), z = sigm(pz);
  float n = ftanh(pin + r * phn);
  return (1.f - z) * n + z * hp;
}
DEV u64 pack8f8(const float* s) {
  u64 p = 0;
  #pragma unroll
  for (int e = 0; e < 8; ++e) p |= (u64)f2e4m3(s[e]) << (8 * e);
  return p;
}

// ---------------------------------------------------------------- MFMA helpers
DEV f32x4 MFMA(short8 a, short8 b, f32x4 c) {
  return __builtin_amdgcn_mfma_f32_16x16x32_bf16(
      __builtin_bit_cast(bf16x8, a), __builtin_bit_cast(bf16x8, b), c, 0, 0, 0);
}
DEV f32x4 mfma8(long a, long b, f32x4 c) {       // A=rows(j), B=cols(batch)
  return __builtin_amdgcn_mfma_f32_16x16x32_fp8_fp8(a, b, c, 0, 0, 0);
}
DEV short8 ldfrag(const u16* p0, int stride) {
  const int l = threadIdx.x & 63;
  const u16* p = p0 + (size_t)(l & 15) * stride + ((l >> 4) << 3);
  return *reinterpret_cast<const short8*>(p);
}
DEV short8 ldfrag_f32(const float* p0, int stride) {
  const int l = threadIdx.x & 63;
  const float* p = p0 + (size_t)(l & 15) * stride + ((l >> 4) << 3);
  f32x4 a = *reinterpret_cast<const f32x4*>(p);
  f32x4 b = *reinterpret_cast<const f32x4*>(p + 4);
  short8 r;
  r[0]=(short)f2bf(a[0]); r[1]=(short)f2bf(a[1]); r[2]=(short)f2bf(a[2]); r[3]=(short)f2bf(a[3]);
  r[4]=(short)f2bf(b[0]); r[5]=(short)f2bf(b[1]); r[6]=(short)f2bf(b[2]); r[7]=(short)f2bf(b[3]);
  return r;
}
// coalesced swizzled-weight readers (fragment-linear)
// K=256: tile=16 rows (4096B); pair p holds kk=2p (.x) and kk=2p+1 (.y); 16B/lane
DEV longx2 ldws2(const u8* w, int tile, int p) {
  return *(const longx2*)(w + ((size_t)tile << 12) + (p << 10) + ((threadIdx.x & 63) << 4));
}
// K=64: tile 1024B; single pair (k2=0 .x, k2=1 .y)
DEV longx2 ldws64x(const u8* w, int tile) {
  return *(const longx2*)(w + ((size_t)tile << 10) + ((threadIdx.x & 63) << 4));
}
// ---------- fragment-native LDS layout (16-row groups, 8B k-chunks) ----------
DEV int fragoff(int row, int jb) { return jb * 128 + ((row ^ (jb & 15)) << 3); }
DEV long ldsF(const u8* m, int r0, int rs, int kk) {
  int l = threadIdx.x & 63;
  int jb = kk * 4 + (l >> 4);
  return *(const long*)(m + ((r0 >> 4) << (rs + 4)) + fragoff(l & 15, jb));
}
DEV void stF(u8* m, int row, int col, unsigned v) {
  *(unsigned*)(m + fragoff(row, col >> 3) + (col & 7)) = v;
}
// bf16 helpers for k_gx
DEV short8 ldsB16(const u8* m, int r0, int kk) {
  int l = threadIdx.x & 63;
  int row = r0 + (l & 15);
  int off = row * 512 + kk * 64 + ((l >> 4) << 4);
  off ^= (row & 7) << 4;
  return *(const short8*)(m + off);
}
DEV void stage16(u8* dst, const u8* src, int nbytes) {
  for (int i = threadIdx.x * 16; i < nbytes; i += blockDim.x * 16) {
    int row = i >> 9;
    int off = i ^ ((row & 7) << 4);
    *(f32x4*)(dst + off) = *(const f32x4*)(src + i);
  }
}

// ---------------------------------------------------------------- k_init
__global__ __launch_bounds__(256) void k_init(Params P) {
  const size_t g  = (size_t)blockIdx.x * 256 + threadIdx.x;
  const size_t gs = (size_t)gridDim.x * 256;
  // x [B,T,D] f32 -> Xf8 [T,B,D] (linear)
  for (size_t i = g; i < 4194304ull; i += gs) {
    size_t flat = i << 3;
    int b = (int)(flat >> 17);
    int rem = (int)(flat & 131071);
    int t = rem >> 8, d = rem & 255;
    *(u64*)(P.Xf8 + (((size_t)t * 256 + b) << 8) + d) = pack8f8(P.x + flat);
  }
  // eps swizzled: 16B unit o -> [t][btile][k2][lane]
  for (size_t o = g; o < 1048576ull; o += gs) {
    int l = (int)(o & 63), k2 = (int)((o >> 6) & 1);
    int bt = (int)((o >> 7) & 15), t = (int)(o >> 11);
    int row = bt * 16 + (l & 15), col = k2 * 32 + ((l >> 4) << 3);
    const float* s = P.eps + ((size_t)t * 256 + row) * 64 + col;
    f32x4 v0 = *(const f32x4*)s, v1 = *(const f32x4*)(s + 4);
    short8 ob;
    ob[0]=(short)f2bf(v0[0]); ob[1]=(short)f2bf(v0[1]); ob[2]=(short)f2bf(v0[2]); ob[3]=(short)f2bf(v0[3]);
    ob[4]=(short)f2bf(v1[0]); ob[5]=(short)f2bf(v1[1]); ob[6]=(short)f2bf(v1[2]); ob[7]=(short)f2bf(v1[3]);
    *(short8*)((u8*)P.ebf + o * 16) = ob;
  }
  const int gi = (int)g, gsi = (int)gs;
  // big K=256 weights, swizzled: long i -> tile,kk,l; byte = tile*4096+(kk>>1)*1024+l*16+(kk&1)*8
  for (int i = gi; i < 24576; i += gsi) {
    int l = i & 63, kk = (i >> 6) & 7, tile = i >> 9;
    int row = tile * 16 + (l & 15), col = kk * 32 + ((l >> 4) << 3);
    size_t so = (size_t)row * 256 + col;
    size_t db = ((size_t)tile << 12) + ((kk >> 1) << 10) + (l << 4) + ((kk & 1) << 3);
    *(u64*)(P.whhc8  + db) = pack8f8(P.Whh_c  + so);
    *(u64*)(P.whhg8  + db) = pack8f8(P.Whh_g  + so);
    *(u64*)(P.wihef8 + db) = pack8f8(P.Wih_ef + so);
    *(u64*)(P.whhef8 + db) = pack8f8(P.Whh_ef + so);
    *(u64*)(P.wiheb8 + db) = pack8f8(P.Wih_eb + so);
    *(u64*)(P.whheb8 + db) = pack8f8(P.Whh_eb + so);
  }
  // heads / W_f (64x256), swizzled
  for (int i = gi; i < 2048; i += gsi) {
    int l = i & 63, kk = (i >> 6) & 7, tile = i >> 9;
    int row = tile * 16 + (l & 15), col = kk * 32 + ((l >> 4) << 3);
    size_t so = (size_t)row * 256 + col;
    size_t db = ((size_t)tile << 12) + ((kk >> 1) << 10) + (l << 4) + ((kk & 1) << 3);
    *(u64*)(P.wf8   + db) = pack8f8(P.W_f   + so);
    *(u64*)(P.wcmu8 + db) = pack8f8(P.W_cmu + so);
    *(u64*)(P.wclv8 + db) = pack8f8(P.W_clv + so);
  }
  // K=64 weights (768x64), swizzled: byte = tile*1024 + l*16 + k2*8
  for (int i = gi; i < 6144; i += gsi) {
    int l = i & 63, k2 = (i >> 6) & 1, tile = i >> 7;
    int row = tile * 16 + (l & 15), col = k2 * 32 + ((l >> 4) << 3);
    size_t db = ((size_t)tile << 10) + (l << 4) + (k2 << 3);
    *(u64*)(P.wihcf8 + db) = pack8f8(P.Wih_c + (size_t)row * 320 + 256 + col);
    *(u64*)(P.wihg8  + db) = pack8f8(P.Wih_g + (size_t)row * 64 + col);
  }
  for (int i = gi; i < 196608; i += gsi) {
    int r = i >> 8, c = i & 255;
    P.wihcbf[i] = f2bf(P.Wih_c[r * 320 + c]);
  }
  for (int i = gi; i < 16384; i += gsi) P.wrbf[i] = f2bf(P.W_r[i]);
  for (int i = gi; i < 768; i += gsi)
    P.bfc[i] = P.bih_c[i] + (i < 512 ? P.bhh_c[i] : 0.f);
  for (int i = gi; i < 256; i += gsi) {
    P.cbn[i] = P.bhh_c[512 + i];
    P.gb[i]        = P.bih_g[i] + P.bhh_g[i];
    P.gb[256 + i]  = P.bih_g[256 + i] + P.bhh_g[256 + i];
    P.gb[512 + i]  = P.bih_g[512 + i];
    P.gb[768 + i]  = P.bhh_g[512 + i];
    P.eb[i]        = P.bih_ef[i] + P.bhh_ef[i];
    P.eb[256 + i]  = P.bih_ef[256 + i] + P.bhh_ef[256 + i];
    P.eb[512 + i]  = P.bih_ef[512 + i];
    P.eb[768 + i]  = P.bhh_ef[512 + i];
    P.eb[1024 + i] = P.bih_eb[i] + P.bhh_eb[i];
    P.eb[1280 + i] = P.bih_eb[256 + i] + P.bhh_eb[256 + i];
    P.eb[1536 + i] = P.bih_eb[512 + i];
    P.eb[1792 + i] = P.bhh_eb[512 + i];
  }
  for (int i = gi; i < 128; i += gsi) P.hdb[i] = (i < 64) ? P.b_cmu[i] : P.b_clv[i - 64];
  for (int i = gi; i < 64; i += gsi)  P.fb2[i] = P.b_f[i];
}

// ---------------------------------------------------------------- k_gx
__global__ __launch_bounds__(512, 2) void k_gx(Params P) {
  extern __shared__ char smem[];
  u8* sA = (u8*)smem;
  u8* sB = sA + 65536;
  const int nc = blockIdx.x % 6;
  const int tb = blockIdx.x / 6;
  const int t = tb >> 1, bh = tb & 1;
  stage16(sA, (const u8*)(P.wihcbf + (size_t)nc * 128 * 256), 65536);
  for (int i = threadIdx.x * 8; i < 32768; i += 512 * 8) {
    int r = i >> 8, c = i & 255;
    const float* s = P.x + ((size_t)(bh * 128 + r) * 512 + t) * 256 + c;
    f32x4 v0 = *(const f32x4*)s, v1 = *(const f32x4*)(s + 4);
    short8 o;
    o[0]=(short)f2bf(v0[0]); o[1]=(short)f2bf(v0[1]); o[2]=(short)f2bf(v0[2]); o[3]=(short)f2bf(v0[3]);
    o[4]=(short)f2bf(v1[0]); o[5]=(short)f2bf(v1[1]); o[6]=(short)f2bf(v1[2]); o[7]=(short)f2bf(v1[3]);
    int off = (r * 512 + c * 2) ^ ((r & 7) << 4);
    *(short8*)(sB + off) = o;
  }
  __syncthreads();
  const int lane = threadIdx.x & 63, wid = threadIdx.x >> 6;
  const int rq = (lane >> 4) << 2;
  const int nglob = nc * 128 + wid * 16;
  short8 Af[8];
  #pragma unroll
  for (int kk = 0; kk < 8; ++kk) Af[kk] = ldsB16(sA, wid * 16, kk);
  float bq[4];
  #pragma unroll
  for (int q = 0; q < 4; ++q) bq[q] = P.bfc[nglob + rq + q];
  #pragma unroll 1
  for (int bt = 0; bt < 8; ++bt) {
    f32x4 acc = {0.f, 0.f, 0.f, 0.f};
    #pragma unroll
    for (int kk = 0; kk < 8; ++kk)
      acc = MFMA(Af[kk], ldsB16(sB, bt * 16, kk), acc);
    float v0 = acc[0] + bq[0], v1 = acc[1] + bq[1], v2 = acc[2] + bq[2], v3 = acc[3] + bq[3];
    unsigned pw = pk2fp8<false>(v0, v1, 0u); pw = pk2fp8<true>(v2, v3, pw);
    // swizzled Gxc: [t][btile][jtile16][lane]; dest lane == producer lane
    *(u32*)(P.Gxc + (((size_t)(t * 16 + bh * 8 + bt) * 48 + (nglob >> 4)) << 8) + (lane << 2)) = pw;
  }
}

// ---------------------------------------------------------------- k_main
DEV void cg_role(const Params& P, int blk, char* smem) {
  u8* hc8  = (u8*)smem;                 // 2*4096
  u8* hg8  = hc8 + 8192;                // 2*4096
  u8* f8b  = hg8 + 8192;                // 2*1024
  float* sml  = (float*)(f8b + 2048);   // 16*132*4
  float* sred = sml + 16 * 132;

  const int lane = threadIdx.x & 63, wid = threadIdx.x >> 6;  // 8 waves
  const int cl = lane & 15, rq = (lane >> 4) << 2;
  const int b0 = blk << 4, j0 = wid << 5, jt = wid << 1;
  const int sel = wid >> 2, l0 = (wid & 3) << 4;

  for (int i = threadIdx.x * 4; i < 18432; i += 512 * 4) *(int*)(hc8 + i) = 0;

  // resident biases
  f32x4 bnv[2], brv[2], bzv[2], biv[2], bhv2[2];
  #pragma unroll
  for (int c2 = 0; c2 < 2; ++c2) {
    int j = j0 + c2 * 16 + rq;
    bnv[c2]  = *(const f32x4*)(P.cbn + j);
    brv[c2]  = *(const f32x4*)(P.gb + j);
    bzv[c2]  = *(const f32x4*)(P.gb + 256 + j);
    biv[c2]  = *(const f32x4*)(P.gb + 512 + j);
    bhv2[c2] = *(const f32x4*)(P.gb + 768 + j);
  }
  f32x4 hbv = *(const f32x4*)(P.hdb + sel * 64 + l0 + rq);
  f32x4 fbv = {0, 0, 0, 0};
  if (wid < 4) fbv = *(const f32x4*)(P.fb2 + wid * 16 + rq);

  f32x4 hcM[2] = {{0,0,0,0},{0,0,0,0}};
  f32x4 hgM[2] = {{0,0,0,0},{0,0,0,0}};
  float klv = 0.f;
  __syncthreads();

  #pragma unroll 1
  for (int t = 0; t < 512; ++t) {
    const int cur = t & 1, prv = cur ^ 1;
    u8 *hcP = hc8 + prv * 4096, *hcC = hc8 + cur * 4096;
    u8 *hgP = hg8 + prv * 4096, *hgC = hg8 + cur * 4096;
    int zz = 0; asm volatile("" : "+v"(zz));       // defeat LICM: stream weights per step
    const u8* wcS = P.whhc8 + zz;
    const u8* wgS = P.whhg8 + zz;
    const u8* cfS = P.wihcf8 + zz;
    const u8* guS = P.wihg8 + zz;
    const u8* hdS = (sel ? P.wclv8 : P.wcmu8) + zz;
    const u8* wfS = P.wf8 + zz;
    // early coalesced loads: Gxc (swizzled) + eps (swizzled)
    u32 gx[6];
    { const u8* gp = P.Gxc + (((size_t)(t * 16 + blk) * 48) << 8) + (lane << 2);
      #pragma unroll
      for (int c2 = 0; c2 < 2; ++c2)
        #pragma unroll
        for (int g3 = 0; g3 < 3; ++g3)
          gx[c2 * 3 + g3] = *(const u32*)(gp + ((g3 * 16 + jt + c2) << 8));
    }
    short8 ee0 = *(const short8*)((const u8*)P.ebf + (((size_t)(t * 16 + blk) * 2 + 0) << 10) + lane * 16);
    short8 ee1 = *(const short8*)((const u8*)P.ebf + (((size_t)(t * 16 + blk) * 2 + 1) << 10) + lane * 16);
    // ---- P1: controller GRU ----
    long hf[8];
    #pragma unroll
    for (int kk = 0; kk < 8; ++kk) hf[kk] = ldsF(hcP, 0, 8, kk);
    long ff0 = ldsF(f8b + prv * 1024, 0, 6, 0);
    long ff1 = ldsF(f8b + prv * 1024, 0, 6, 1);
    #pragma unroll
    for (int c2 = 0; c2 < 2; ++c2) {
      longx2 w0[4], w1[4], w2[4];
      #pragma unroll
      for (int p = 0; p < 4; ++p) {
        w0[p] = ldws2(wcS,      jt + c2, p);
        w1[p] = ldws2(wcS, 16 + jt + c2, p);
        w2[p] = ldws2(wcS, 32 + jt + c2, p);
      }
      longx2 cf0 = ldws64x(cfS,      jt + c2);
      longx2 cf1 = ldws64x(cfS, 16 + jt + c2);
      longx2 cf2 = ldws64x(cfS, 32 + jt + c2);
      f32x4 ar = {0,0,0,0}, az = {0,0,0,0}, ai = {0,0,0,0}, ah = {0,0,0,0};
      #pragma unroll
      for (int p = 0; p < 4; ++p) {
        ar = mfma8(w0[p].x, hf[2*p], ar);  ar = mfma8(w0[p].y, hf[2*p+1], ar);
        az = mfma8(w1[p].x, hf[2*p], az);  az = mfma8(w1[p].y, hf[2*p+1], az);
        ah = mfma8(w2[p].x, hf[2*p], ah);  ah = mfma8(w2[p].y, hf[2*p+1], ah);
      }
      ar = mfma8(cf0.x, ff0, ar); ar = mfma8(cf0.y, ff1, ar);
      az = mfma8(cf1.x, ff0, az); az = mfma8(cf1.y, ff1, az);
      ai = mfma8(cf2.x, ff0, ai); ai = mfma8(cf2.y, ff1, ai);
      f32x2 rlo = pkf32<false>(gx[c2*3+0]), rhi = pkf32<true>(gx[c2*3+0]);
      f32x2 zlo = pkf32<false>(gx[c2*3+1]), zhi = pkf32<true>(gx[c2*3+1]);
      f32x2 nlo = pkf32<false>(gx[c2*3+2]), nhi = pkf32<true>(gx[c2*3+2]);
      f32x4 bn = bnv[c2];
      float h0 = gru_h(ar[0]+rlo[0], az[0]+zlo[0], ai[0]+nlo[0], ah[0]+bn[0], hcM[c2][0]);
      float h1 = gru_h(ar[1]+rlo[1], az[1]+zlo[1], ai[1]+nlo[1], ah[1]+bn[1], hcM[c2][1]);
      float h2 = gru_h(ar[2]+rhi[0], az[2]+zhi[0], ai[2]+nhi[0], ah[2]+bn[2], hcM[c2][2]);
      float h3 = gru_h(ar[3]+rhi[1], az[3]+zhi[1], ai[3]+nhi[1], ah[3]+bn[3], hcM[c2][3]);
      hcM[c2][0] = h0; hcM[c2][1] = h1; hcM[c2][2] = h2; hcM[c2][3] = h3;
      unsigned pw = pk2fp8<false>(h0, h1, 0u); pw = pk2fp8<true>(h2, h3, pw);
      stF(hcC, cl, j0 + c2 * 16 + rq, pw);
    }
    __syncthreads();                                    // B1
    // ---- P2: heads -> sml ----
    { long hcv[8];
      #pragma unroll
      for (int kk = 0; kk < 8; ++kk) hcv[kk] = ldsF(hcC, 0, 8, kk);
      f32x4 am = {0,0,0,0};
      #pragma unroll
      for (int p = 0; p < 4; ++p) {
        longx2 wp = ldws2(hdS, wid & 3, p);
        am = mfma8(wp.x, hcv[2*p], am);
        am = mfma8(wp.y, hcv[2*p+1], am);
      }
      am += hbv;
      *(f32x4*)(sml + cl * 132 + sel * 64 + l0 + rq) = am;
    }
    __syncthreads();                                    // B2
    // ---- P3: u + generator GRU ----
    long U[2];
    { const float* ml = sml + cl * 132;
      const int kh = (lane >> 4) << 3;
      #pragma unroll
      for (int k2 = 0; k2 < 2; ++k2) {
        f32x4 mu0 = *(const f32x4*)(ml + k2 * 32 + kh);
        f32x4 mu1 = *(const f32x4*)(ml + k2 * 32 + kh + 4);
        f32x4 lv0 = *(const f32x4*)(ml + 64 + k2 * 32 + kh);
        f32x4 lv1 = *(const f32x4*)(ml + 64 + k2 * 32 + kh + 4);
        short8 ev = k2 ? ee1 : ee0;
        float uu[8];
        #pragma unroll
        for (int e = 0; e < 4; ++e) {
          float epv = bf2f((u32)(u16)ev[e]);
          uu[e] = mu0[e] + epv * __expf(0.5f * lv0[e]);
        }
        #pragma unroll
        for (int e = 0; e < 4; ++e) {
          float epv = bf2f((u32)(u16)ev[4 + e]);
          uu[4 + e] = mu1[e] + epv * __expf(0.5f * lv1[e]);
        }
        unsigned pa = pk2fp8<false>(uu[0], uu[1], 0u); pa = pk2fp8<true>(uu[2], uu[3], pa);
        unsigned pb = pk2fp8<false>(uu[4], uu[5], 0u); pb = pk2fp8<true>(uu[6], uu[7], pb);
        U[k2] = (long)(((u64)pb << 32) | (u64)pa);
      }
    }
    long hg[8];
    #pragma unroll
    for (int kk = 0; kk < 8; ++kk) hg[kk] = ldsF(hgP, 0, 8, kk);
    #pragma unroll
    for (int c2 = 0; c2 < 2; ++c2) {
      longx2 g0[4], g1[4], g2[4];
      #pragma unroll
      for (int p = 0; p < 4; ++p) {
        g0[p] = ldws2(wgS,      jt + c2, p);
        g1[p] = ldws2(wgS, 16 + jt + c2, p);
        g2[p] = ldws2(wgS, 32 + jt + c2, p);
      }
      longx2 u0 = ldws64x(guS,      jt + c2);
      longx2 u1 = ldws64x(guS, 16 + jt + c2);
      longx2 u2 = ldws64x(guS, 32 + jt + c2);
      f32x4 gr = {0,0,0,0}, gz = {0,0,0,0}, gi = {0,0,0,0}, gh = {0,0,0,0};
      #pragma unroll
      for (int p = 0; p < 4; ++p) {
        gr = mfma8(g0[p].x, hg[2*p], gr);  gr = mfma8(g0[p].y, hg[2*p+1], gr);
        gz = mfma8(g1[p].x, hg[2*p], gz);  gz = mfma8(g1[p].y, hg[2*p+1], gz);
        gh = mfma8(g2[p].x, hg[2*p], gh);  gh = mfma8(g2[p].y, hg[2*p+1], gh);
      }
      gr = mfma8(u0.x, U[0], gr); gr = mfma8(u0.y, U[1], gr);
      gz = mfma8(u1.x, U[0], gz); gz = mfma8(u1.y, U[1], gz);
      gi = mfma8(u2.x, U[0], gi); gi = mfma8(u2.y, U[1], gi);
      float h0 = gru_h(gr[0]+brv[c2][0], gz[0]+bzv[c2][0], gi[0]+biv[c2][0], gh[0]+bhv2[c2][0], hgM[c2][0]);
      float h1 = gru_h(gr[1]+brv[c2][1], gz[1]+bzv[c2][1], gi[1]+biv[c2][1], gh[1]+bhv2[c2][1], hgM[c2][1]);
      float h2 = gru_h(gr[2]+brv[c2][2], gz[2]+bzv[c2][2], gi[2]+biv[c2][2], gh[2]+bhv2[c2][2], hgM[c2][2]);
      float h3 = gru_h(gr[3]+brv[c2][3], gz[3]+bzv[c2][3], gi[3]+biv[c2][3], gh[3]+bhv2[c2][3], hgM[c2][3]);
      hgM[c2][0] = h0; hgM[c2][1] = h1; hgM[c2][2] = h2; hgM[c2][3] = h3;
      unsigned pw = pk2fp8<false>(h0, h1, 0u); pw = pk2fp8<true>(h2, h3, pw);
      stF(hgC, cl, j0 + c2 * 16 + rq, pw);
    }
    __syncthreads();                                    // B3
    // ---- P4: factors + KL ----
    if (wid < 4) {
      long hgv[8];
      #pragma unroll
      for (int kk = 0; kk < 8; ++kk) hgv[kk] = ldsF(hgC, 0, 8, kk);
      f32x4 af = {0,0,0,0};
      #pragma unroll
      for (int p = 0; p < 4; ++p) {
        longx2 wp = ldws2(wfS, wid, p);
        af = mfma8(wp.x, hgv[2*p], af);
        af = mfma8(wp.y, hgv[2*p+1], af);
      }
      af += fbv;
      float* fo = P.out + FOUT + (size_t)(b0 + cl) * 32768 + (size_t)t * 64 + wid * 16 + rq;
      f32x2 lo = {af[0], af[1]}, hi2 = {af[2], af[3]};
      *(f32x2*)fo = lo;
      *(f32x2*)(fo + 2) = hi2;
      unsigned pw = pk2fp8<false>(af[0], af[1], 0u); pw = pk2fp8<true>(af[2], af[3], pw);
      stF(f8b + cur * 1024, cl, wid * 16 + rq, pw);
    } else {
      #pragma unroll
      for (int e = 0; e < 4; ++e) {
        int p = ((wid - 4) * 64 + lane) * 4 + e;
        int row = p >> 6, l = p & 63;
        float mu = sml[row * 132 + l], lv = sml[row * 132 + 64 + l];
        klv += __expf(lv) + mu * mu - 1.f - lv;
      }
    }
    __syncthreads();                                    // B4
  }
  if (wid >= 4) {
    float v = klv;
    v += __shfl_down(v, 32); v += __shfl_down(v, 16); v += __shfl_down(v, 8);
    v += __shfl_down(v, 4);  v += __shfl_down(v, 2);  v += __shfl_down(v, 1);
    if (lane == 0) sred[wid] = v;
  }
  __syncthreads();
  if (threadIdx.x == 0) P.klacc[blk] = sred[4] + sred[5] + sred[6] + sred[7];
}

DEV void enc_role(const Params& P, int dir, int b0, char* smem) {
  u8* h8 = (u8*)smem;                   // 2*4096 state
  u8* sx = h8 + 8192;                   // 2*4096 x dbuf
  const int lane = threadIdx.x & 63, wid = threadIdx.x >> 6;
  const int cl = lane & 15, rq = (lane >> 4) << 2;
  const int j0 = wid << 5, jt = wid << 1;
  const u8* wihS0 = dir ? P.wiheb8 : P.wihef8;
  const u8* whhS0 = dir ? P.whheb8 : P.whhef8;
  const float* ebt = P.eb + dir * 1024;
  for (int i = threadIdx.x * 4; i < 8192; i += 512 * 4) *(int*)(h8 + i) = 0;
  f32x4 brv[2], bzv[2], biv[2], bhv2[2];
  #pragma unroll
  for (int c2 = 0; c2 < 2; ++c2) {
    int j = j0 + c2 * 16 + rq;
    brv[c2]  = *(const f32x4*)(ebt + j);
    bzv[c2]  = *(const f32x4*)(ebt + 256 + j);
    biv[c2]  = *(const f32x4*)(ebt + 512 + j);
    bhv2[c2] = *(const f32x4*)(ebt + 768 + j);
  }
  f32x4 heM[2] = {{0,0,0,0},{0,0,0,0}};
  const int ssrc = threadIdx.x * 8;
  const int sdst = fragoff(threadIdx.x >> 5, threadIdx.x & 31);
  const int t0 = dir ? 511 : 0;
  *(u64*)(sx + sdst) = *(const u64*)(P.Xf8 + (((size_t)t0 * 256 + b0) << 8) + ssrc);
  __syncthreads();

  #pragma unroll 1
  for (int i = 0; i < 512; ++i) {
    const int cur = i & 1, prv = cur ^ 1;
    const int t = dir ? (511 - i) : i;
    u8 *hP = h8 + prv * 4096, *hC = h8 + cur * 4096;
    const u8* sxc = sx + cur * 4096;
    int zz = 0; asm volatile("" : "+v"(zz));
    const u8* wihS = wihS0 + zz;
    const u8* whhS = whhS0 + zz;
    u64 xpre = 0;
    if (i < 511) {
      int tn = dir ? (t - 1) : (t + 1);
      xpre = *(const u64*)(P.Xf8 + (((size_t)tn * 256 + b0) << 8) + ssrc);
    }
    long hp[8], xv[8];
    #pragma unroll
    for (int kk = 0; kk < 8; ++kk) { hp[kk] = ldsF(hP, 0, 8, kk); xv[kk] = ldsF(sxc, 0, 8, kk); }
    #pragma unroll
    for (int c2 = 0; c2 < 2; ++c2) {
      longx2 H0[4], H1[4], H2[4], I0[4], I1[4], I2[4];
      #pragma unroll
      for (int p = 0; p < 4; ++p) {
        H0[p] = ldws2(whhS,      jt + c2, p);
        H1[p] = ldws2(whhS, 16 + jt + c2, p);
        H2[p] = ldws2(whhS, 32 + jt + c2, p);
        I0[p] = ldws2(wihS,      jt + c2, p);
        I1[p] = ldws2(wihS, 16 + jt + c2, p);
        I2[p] = ldws2(wihS, 32 + jt + c2, p);
      }
      f32x4 er = {0,0,0,0}, ez = {0,0,0,0}, ei = {0,0,0,0}, eh = {0,0,0,0};
      #pragma unroll
      for (int p = 0; p < 4; ++p) {
        er = mfma8(H0[p].x, hp[2*p], er);  er = mfma8(H0[p].y, hp[2*p+1], er);
        ez = mfma8(H1[p].x, hp[2*p], ez);  ez = mfma8(H1[p].y, hp[2*p+1], ez);
        eh = mfma8(H2[p].x, hp[2*p], eh);  eh = mfma8(H2[p].y, hp[2*p+1], eh);
        er = mfma8(I0[p].x, xv[2*p], er);  er = mfma8(I0[p].y, xv[2*p+1], er);
        ez = mfma8(I1[p].x, xv[2*p], ez);  ez = mfma8(I1[p].y, xv[2*p+1], ez);
        ei = mfma8(I2[p].x, xv[2*p], ei);  ei = mfma8(I2[p].y, xv[2*p+1], ei);
      }
      float h0 = gru_h(er[0]+brv[c2][0], ez[0]+bzv[c2][0], ei[0]+biv[c2][0], eh[0]+bhv2[c2][0], heM[c2][0]);
      float h1 = gru_h(er[1]+brv[c2][1], ez[1]+bzv[c2][1], ei[1]+biv[c2][1], eh[1]+bhv2[c2][1], heM[c2][1]);
      float h2 = gru_h(er[2]+brv[c2][2], ez[2]+bzv[c2][2], ei[2]+biv[c2][2], eh[2]+bhv2[c2][2], heM[c2][2]);
      float h3 = gru_h(er[3]+brv[c2][3], ez[3]+bzv[c2][3], ei[3]+biv[c2][3], eh[3]+bhv2[c2][3], heM[c2][3]);
      heM[c2][0] = h0; heM[c2][1] = h1; heM[c2][2] = h2; heM[c2][3] = h3;
      unsigned pw = pk2fp8<false>(h0, h1, 0u); pw = pk2fp8<true>(h2, h3, pw);
      stF(hC, cl, j0 + c2 * 16 + rq, pw);
    }
    if (i < 511) *(u64*)(sx + prv * 4096 + sdst) = xpre;
    __syncthreads();
  }
  #pragma unroll
  for (int c2 = 0; c2 < 2; ++c2)
    *(f32x4*)(P.henc + (size_t)(dir * 256 + b0 + cl) * 256 + j0 + c2 * 16 + rq) = heM[c2];
}

__global__ __launch_bounds__(512, 2) void k_main(Params P) {
  extern __shared__ char smem[];
  const int blk = blockIdx.x;
  if (blk < 16) cg_role(P, blk, smem);
  else {
    const int e = blk - 16;
    enc_role(P, e >> 4, (e & 15) << 4, smem);
  }
}

// ---------------------------------------------------------------- k_post
__global__ __launch_bounds__(256) void k_post(Params P) {
  const int blk = blockIdx.x;
  if (blk < 32) {
    __shared__ float red[4];
    float ka = 0.f;
    #pragma unroll 1
    for (int pp = 0; pp < 2; ++pp) {
      int p = blk * 512 + threadIdx.x * 2 + pp;
      int b = p >> 6, l = p & 63;
      float mu = P.b_mu0[l], lv = P.b_lv0[l];
      const float* wm = P.W_mu0 + (size_t)l * 512;
      const float* wl = P.W_lv0 + (size_t)l * 512;
      const float* h0 = P.henc + (size_t)b * 256;
      const float* h1 = P.henc + (size_t)(256 + b) * 256;
      #pragma unroll 4
      for (int k = 0; k < 256; ++k) {
        float hf = h0[k], hb = h1[k];
        mu += hf * wm[k] + hb * wm[256 + k];
        lv += hf * wl[k] + hb * wl[256 + k];
      }
      ka += __expf(lv) + mu * mu - 1.f - lv;
    }
    const int lane = threadIdx.x & 63, wid = threadIdx.x >> 6;
    ka += __shfl_down(ka, 32); ka += __shfl_down(ka, 16); ka += __shfl_down(ka, 8);
    ka += __shfl_down(ka, 4);  ka += __shfl_down(ka, 2);  ka += __shfl_down(ka, 1);
    if (lane == 0) red[wid] = ka;
    __syncthreads();
    if (threadIdx.x == 0) P.klics[blk] = red[0] + red[1] + red[2] + red[3];
  } else {
    const int lane = threadIdx.x & 63, wid = threadIdx.x >> 6;
    const int cl = lane & 15, rq = (lane >> 4) << 2;
    const int gw = (blk - 32) * 4 + wid;
    const size_t r0 = (size_t)gw << 4;
    const float* Fs = P.out + FOUT;
    short8 F0 = ldfrag_f32(Fs + r0 * 64, 64);
    short8 F1 = ldfrag_f32(Fs + r0 * 64 + 32, 64);
    #pragma unroll 1
    for (int ct = 0; ct < 16; ++ct) {
      const int d0 = ct << 4;
      const u16* W = P.wrbf + (size_t)d0 * 64;
      f32x4 a = {0,0,0,0};
      a = MFMA(ldfrag(W, 64), F0, a);
      a = MFMA(ldfrag(W + 32, 64), F1, a);
      f32x4 rb = *(const f32x4*)(P.b_r + d0 + rq);
      f32x4 o;
      o[0] = __expf(a[0] + rb[0]); o[1] = __expf(a[1] + rb[1]);
      o[2] = __expf(a[2] + rb[2]); o[3] = __expf(a[3] + rb[3]);
      *(f32x4*)(P.out + (r0 + cl) * 256 + d0 + rq) = o;
    }
  }
}

__global__ void k_final(Params P) {
  if (threadIdx.x == 0) {
    float s = 0.f, s2 = 0.f;
    for (int i = 0; i < 16; ++i) s += P.klacc[i];
    for (int i = 0; i < 32; ++i) s2 += P.klics[i];
    P.out[RATES_N]     = s2 * (0.5f / 256.f);
    P.out[RATES_N + 1] = s  * (0.5f / (256.f * 512.f));
  }
}

// ---------------------------------------------------------------- launch
extern "C" void kernel_launch(void* const* d_in, const int* in_sizes, int n_in,
                              void* d_out, int out_size, void* d_ws, size_t ws_size,
                              hipStream_t stream) {
  (void)in_sizes; (void)n_in; (void)out_size; (void)ws_size;
  Params P;
  const float* const* in = (const float* const*)d_in;
  P.x = in[0];      P.eps = in[1];
  P.Wih_ef = in[2]; P.Whh_ef = in[3]; P.bih_ef = in[4]; P.bhh_ef = in[5];
  P.Wih_eb = in[6]; P.Whh_eb = in[7]; P.bih_eb = in[8]; P.bhh_eb = in[9];
  P.W_mu0 = in[10]; P.b_mu0 = in[11]; P.W_lv0 = in[12]; P.b_lv0 = in[13];
  P.Wih_c = in[14]; P.Whh_c = in[15]; P.bih_c = in[16]; P.bhh_c = in[17];
  P.W_cmu = in[18]; P.b_cmu = in[19]; P.W_clv = in[20]; P.b_clv = in[21];
  P.Wih_g = in[22]; P.Whh_g = in[23]; P.bih_g = in[24]; P.bhh_g = in[25];
  P.W_f = in[26];   P.b_f = in[27];   P.W_r = in[28];   P.b_r = in[29];

  char* w = (char*)d_ws;
  size_t off = 0;
  auto take = [&](size_t bytes) -> char* {
    char* r = w + off;
    off = (off + bytes + 255) & ~(size_t)255;
    return r;
  };
  P.Xf8    = (u8*)take(33554432ull);
  P.ebf    = (u16*)take(16777216ull * 2);
  P.wihcbf = (u16*)take(196608ull * 2);
  P.bfc    = (float*)take(768ull * 4);
  P.wihef8 = (u8*)take(196608ull);
  P.whhef8 = (u8*)take(196608ull);
  P.wiheb8 = (u8*)take(196608ull);
  P.whheb8 = (u8*)take(196608ull);
  P.whhc8  = (u8*)take(196608ull);
  P.whhg8  = (u8*)take(196608ull);
  P.wihcf8 = (u8*)take(49152ull);
  P.wihg8  = (u8*)take(49152ull);
  P.wf8    = (u8*)take(16384ull);
  P.wcmu8  = (u8*)take(16384ull);
  P.wclv8  = (u8*)take(16384ull);
  P.wrbf   = (u16*)take(16384ull * 2);
  P.cbn    = (float*)take(256ull * 4);
  P.gb     = (float*)take(1024ull * 4);
  P.hdb    = (float*)take(128ull * 4);
  P.fb2    = (float*)take(64ull * 4);
  P.eb     = (float*)take(2048ull * 4);
  P.henc   = (float*)take(131072ull * 4);
  P.klacc  = (float*)take(64ull * 4);
  P.klics  = (float*)take(64ull * 4);
  P.Gxc    = (u8*)d_out;
  P.out    = (float*)d_out;

  hipLaunchKernelGGL(k_init,  dim3(2048), dim3(256), 0, stream, P);
  hipLaunchKernelGGL(k_gx,    dim3(6144), dim3(512), 131072, stream, P);
  hipLaunchKernelGGL(k_main,  dim3(48),   dim3(512), 27008, stream, P);
  hipLaunchKernelGGL(k_post,  dim3(2080), dim3(256), 0, stream, P);
  hipLaunchKernelGGL(k_final, dim3(1),    dim3(64),  0, stream, P);
}